// Round 1
// baseline (116.901 us; speedup 1.0000x reference)
//
#include <hip/hip_runtime.h>

// Output: diag(d), N x N fp32, where
// d = -params*r_mask + ics_mask + triggers*vcsw_mask + vc_mask
//
// Pure HBM-write-bound: 604 MB per call. Reference ceiling: the harness's
// own fillBufferAligned memset hits 6.75-6.80 TB/s on this chip; v1 of this
// kernel (1 float4 store/thread, 147K blocks) reached only 6.21 TB/s.
// This version amortizes per-block overhead: 1 block per row, each thread
// streams 12 nontemporal float4 stores (48 KB/block), diagonal injected
// branch-free via a block-uniform iteration select.
static constexpr int N = 12288;
static constexpr int F4_PER_ROW = N / 4;          // 3072 float4 per row
static constexpr int BLOCK = 256;
static constexpr int ITERS = F4_PER_ROW / BLOCK;  // 12 stores per thread

typedef float vfloat4 __attribute__((ext_vector_type(4)));

__global__ __launch_bounds__(BLOCK)
void impedance_fused_kernel(const float* __restrict__ params,
                            const float* __restrict__ triggers,
                            const float* __restrict__ r_mask,
                            const float* __restrict__ ics_mask,
                            const float* __restrict__ vcsw_mask,
                            const float* __restrict__ vc_mask,
                            float* __restrict__ out) {
    const int row = blockIdx.x;          // 0..N-1, uniform per block
    const int tid = threadIdx.x;         // 0..255

    // Diagonal element (row, row) lives in float4 index dq of this row,
    // covered by thread (dq & 255) at loop iteration (dq >> 8).
    const int dq    = row >> 2;          // 0..3071, uniform
    const int jq    = dq >> 8;           // 0..11,   uniform  -> scalar compare
    const int owner = dq & (BLOCK - 1);  // uniform

    // row is uniform -> these compile to scalar loads (L2-cached broadcast).
    const float d = fmaf(-params[row], r_mask[row],
                    fmaf(triggers[row], vcsw_mask[row],
                         ics_mask[row] + vc_mask[row]));

    const vfloat4 zerov = (vfloat4)(0.f);
    vfloat4 diagv = zerov;
    if (tid == owner) diagv[row & 3] = d;   // nonzero in exactly one lane

    // Lane-contiguous: at iteration j, lanes 0..255 cover float4 indices
    // j*256 .. j*256+255 -> each wave store is 64 x 16 B = 1 KiB contiguous.
    vfloat4* p = (vfloat4*)(out + (size_t)row * N) + tid;
#pragma unroll
    for (int j = 0; j < ITERS; ++j) {
        vfloat4 v = (j == jq) ? diagv : zerov;   // scalar cmp + cndmask
        __builtin_nontemporal_store(v, p + j * BLOCK);
    }
}

extern "C" void kernel_launch(void* const* d_in, const int* in_sizes, int n_in,
                              void* d_out, int out_size, void* d_ws, size_t ws_size,
                              hipStream_t stream) {
    const float* params    = (const float*)d_in[0];
    const float* triggers  = (const float*)d_in[1];
    const float* r_mask    = (const float*)d_in[2];
    const float* ics_mask  = (const float*)d_in[3];
    const float* vcsw_mask = (const float*)d_in[4];
    const float* vc_mask   = (const float*)d_in[5];
    float* out = (float*)d_out;

    dim3 grid(N, 1, 1);        // one block per row
    dim3 block(BLOCK, 1, 1);
    impedance_fused_kernel<<<grid, block, 0, stream>>>(
        params, triggers, r_mask, ics_mask, vcsw_mask, vc_mask, out);
}